// Round 1
// baseline (104.189 us; speedup 1.0000x reference)
//
#include <hip/hip_runtime.h>

// SO3 encode: z[B, 96] -> (mean[B,16,3,3], logvar[B,16,3])
// mean = Rodrigues(exp of skew([ [0,a,b], [-a,0,c], [-b,-c,0] ]))
// logvar = 5.4*sigmoid(logits) - 9.2
// One thread handles 4 gaussians of one batch row so every global access is
// an aligned float4 (loads 96B, stores 192B per thread).

__global__ __launch_bounds__(256) void so3_encode_kernel(
    const float* __restrict__ z,
    float* __restrict__ out_mean,
    float* __restrict__ out_logvar,
    int nthreads)
{
    int idx = blockIdx.x * blockDim.x + threadIdx.x;
    if (idx >= nthreads) return;
    int b = idx >> 2;   // batch row
    int k = idx & 3;    // which quad of 4 gaussians (of 16)

    // axis params: z[b, k*12 .. k*12+11]  (16B aligned: k*12 floats = k*48 B)
    const float4* za = reinterpret_cast<const float4*>(z + (size_t)b * 96 + k * 12);
    float4 a0 = za[0];
    float4 a1 = za[1];
    float4 a2 = za[2];
    // logvar logits: z[b, 48 + k*12 .. ]
    const float4* zl = reinterpret_cast<const float4*>(z + (size_t)b * 96 + 48 + k * 12);
    float4 l0 = zl[0];
    float4 l1 = zl[1];
    float4 l2 = zl[2];

    float av[12] = {a0.x, a0.y, a0.z, a0.w,
                    a1.x, a1.y, a1.z, a1.w,
                    a2.x, a2.y, a2.z, a2.w};
    float lv[12] = {l0.x, l0.y, l0.z, l0.w,
                    l1.x, l1.y, l1.z, l1.w,
                    l2.x, l2.y, l2.z, l2.w};

    float m[36];
    #pragma unroll
    for (int j = 0; j < 4; ++j) {
        float a  = av[3 * j + 0];
        float bb = av[3 * j + 1];
        float c  = av[3 * j + 2];
        float th2 = a * a + bb * bb + c * c;
        bool small = th2 < 1e-8f;
        float t2 = small ? 1.0f : th2;       // safe denom, matches reference
        float t  = sqrtf(t2);
        float sn, cs;
        __sincosf(t, &sn, &cs);
        float inv_t2 = 1.0f / t2;
        float s1 = small ? (1.0f - th2 * (1.0f / 6.0f))  : (sn * t * inv_t2);      // sin(t)/t
        float s2 = small ? (0.5f - th2 * (1.0f / 24.0f)) : ((1.0f - cs) * inv_t2); // (1-cos t)/t^2

        // mean = I + s1*A + s2*A^2 with
        // A   = [[0,a,b],[-a,0,c],[-b,-c,0]]
        // A^2 = [[-(a^2+b^2), -bc, ac], [-bc, -(a^2+c^2), -ab], [ac, -ab, -(b^2+c^2)]]
        float* o = m + 9 * j;
        float ab = a * bb, ac = a * c, bc = bb * c;
        o[0] = 1.0f - s2 * (a * a + bb * bb);
        o[1] = s1 * a  - s2 * bc;
        o[2] = s1 * bb + s2 * ac;
        o[3] = -s1 * a - s2 * bc;
        o[4] = 1.0f - s2 * (a * a + c * c);
        o[5] = s1 * c  - s2 * ab;
        o[6] = -s1 * bb + s2 * ac;
        o[7] = -s1 * c  - s2 * ab;
        o[8] = 1.0f - s2 * (bb * bb + c * c);
    }

    // mean out: 4 gaussians * 9 = 36 floats, base idx*36 (16B aligned)
    float4* om = reinterpret_cast<float4*>(out_mean + (size_t)idx * 36);
    #pragma unroll
    for (int q = 0; q < 9; ++q) {
        om[q] = make_float4(m[4 * q + 0], m[4 * q + 1], m[4 * q + 2], m[4 * q + 3]);
    }

    // logvar: 5.4*sigmoid(x) - 9.2 over 12 logits, base idx*12 (16B aligned)
    float lg[12];
    #pragma unroll
    for (int j = 0; j < 12; ++j) {
        lg[j] = 5.4f / (1.0f + __expf(-lv[j])) - 9.2f;
    }
    float4* ol = reinterpret_cast<float4*>(out_logvar + (size_t)idx * 12);
    #pragma unroll
    for (int q = 0; q < 3; ++q) {
        ol[q] = make_float4(lg[4 * q + 0], lg[4 * q + 1], lg[4 * q + 2], lg[4 * q + 3]);
    }
}

extern "C" void kernel_launch(void* const* d_in, const int* in_sizes, int n_in,
                              void* d_out, int out_size, void* d_ws, size_t ws_size,
                              hipStream_t stream) {
    const float* z = (const float*)d_in[0];
    const int B = in_sizes[0] / 96;          // 6 * N_GAUSS = 96 floats per row
    float* out_mean = (float*)d_out;                              // B*16*9 floats
    float* out_logvar = (float*)d_out + (size_t)B * 16 * 9;       // B*16*3 floats

    const int nthreads = B * 4;              // one thread per 4 gaussians
    const int block = 256;
    const int grid = (nthreads + block - 1) / block;
    so3_encode_kernel<<<grid, block, 0, stream>>>(z, out_mean, out_logvar, nthreads);
}

// Round 2
// 53.760 us; speedup vs baseline: 1.9380x; 1.9380x over previous
//
#include <hip/hip_runtime.h>

// SO3 encode: z[B, 96] -> (mean[B,16,3,3], logvar[B,16,3])
// mean = I + s1*A + s2*A^2 (Rodrigues), logvar = 5.4*sigmoid(logits) - 9.2
//
// One thread computes 4 gaussians of one row (all loads aligned float4).
// Stores go through LDS so the block writes its contiguous 48 KB output
// region with fully coalesced linear float4 stores (R1 was 144B-strided
// scatter stores -> 2.9 TB/s effective; this targets ~6-7 TB/s).

#define BLOCK 256

__global__ __launch_bounds__(BLOCK) void so3_encode_kernel(
    const float* __restrict__ z,
    float* __restrict__ out_mean,
    float* __restrict__ out_logvar)
{
    __shared__ float lds_m[BLOCK * 36];   // 36 KB: per-thread 9 float4 of mean
    __shared__ float lds_l[BLOCK * 12];   // 12 KB: per-thread 3 float4 of logvar

    const int t = threadIdx.x;
    const int idx = blockIdx.x * BLOCK + t;   // grid is exact: B*4 % 256 == 0
    const int b = idx >> 2;   // batch row
    const int k = idx & 3;    // quad of 4 gaussians (of 16)

    // axis params: z[b, k*12 .. k*12+11]  (byte offset b*384 + k*48, 16B aligned)
    const float4* za = reinterpret_cast<const float4*>(z + (size_t)b * 96 + k * 12);
    float4 a0 = za[0];
    float4 a1 = za[1];
    float4 a2 = za[2];
    // logvar logits: z[b, 48 + k*12 .. ]
    const float4* zl = reinterpret_cast<const float4*>(z + (size_t)b * 96 + 48 + k * 12);
    float4 l0 = zl[0];
    float4 l1 = zl[1];
    float4 l2 = zl[2];

    float av[12] = {a0.x, a0.y, a0.z, a0.w,
                    a1.x, a1.y, a1.z, a1.w,
                    a2.x, a2.y, a2.z, a2.w};
    float lv[12] = {l0.x, l0.y, l0.z, l0.w,
                    l1.x, l1.y, l1.z, l1.w,
                    l2.x, l2.y, l2.z, l2.w};

    float m[36];
    #pragma unroll
    for (int j = 0; j < 4; ++j) {
        float a  = av[3 * j + 0];
        float bb = av[3 * j + 1];
        float c  = av[3 * j + 2];
        float th2 = a * a + bb * bb + c * c;
        bool small = th2 < 1e-8f;
        float t2 = small ? 1.0f : th2;       // safe denom, matches reference
        float tt = sqrtf(t2);
        float sn, cs;
        __sincosf(tt, &sn, &cs);
        float inv_t2 = 1.0f / t2;
        float s1 = small ? (1.0f - th2 * (1.0f / 6.0f))  : (sn * tt * inv_t2);     // sin(t)/t
        float s2 = small ? (0.5f - th2 * (1.0f / 24.0f)) : ((1.0f - cs) * inv_t2); // (1-cos t)/t^2

        float* o = m + 9 * j;
        float ab = a * bb, ac = a * c, bc = bb * c;
        o[0] = 1.0f - s2 * (a * a + bb * bb);
        o[1] = s1 * a  - s2 * bc;
        o[2] = s1 * bb + s2 * ac;
        o[3] = -s1 * a - s2 * bc;
        o[4] = 1.0f - s2 * (a * a + c * c);
        o[5] = s1 * c  - s2 * ab;
        o[6] = -s1 * bb + s2 * ac;
        o[7] = -s1 * c  - s2 * ab;
        o[8] = 1.0f - s2 * (bb * bb + c * c);
    }

    float lg[12];
    #pragma unroll
    for (int j = 0; j < 12; ++j) {
        lg[j] = 5.4f / (1.0f + __expf(-lv[j])) - 9.2f;
    }

    // ---- stage to LDS (thread-stride 36/12 floats: start banks 4t%32,
    //      same phase pattern as contiguous float4 access -> conflict-free)
    float4* lm = reinterpret_cast<float4*>(lds_m + t * 36);
    #pragma unroll
    for (int q = 0; q < 9; ++q)
        lm[q] = make_float4(m[4 * q + 0], m[4 * q + 1], m[4 * q + 2], m[4 * q + 3]);

    float4* ll = reinterpret_cast<float4*>(lds_l + t * 12);
    #pragma unroll
    for (int q = 0; q < 3; ++q)
        ll[q] = make_float4(lg[4 * q + 0], lg[4 * q + 1], lg[4 * q + 2], lg[4 * q + 3]);

    __syncthreads();

    // ---- coalesced writeout: lane t stores byte offset t*16, contiguous per wave
    const float4* lmall = reinterpret_cast<const float4*>(lds_m);
    float4* om = reinterpret_cast<float4*>(out_mean) + (size_t)blockIdx.x * (BLOCK * 9);
    #pragma unroll
    for (int i = 0; i < 9; ++i)
        om[i * BLOCK + t] = lmall[i * BLOCK + t];

    const float4* llall = reinterpret_cast<const float4*>(lds_l);
    float4* ol = reinterpret_cast<float4*>(out_logvar) + (size_t)blockIdx.x * (BLOCK * 3);
    #pragma unroll
    for (int i = 0; i < 3; ++i)
        ol[i * BLOCK + t] = llall[i * BLOCK + t];
}

extern "C" void kernel_launch(void* const* d_in, const int* in_sizes, int n_in,
                              void* d_out, int out_size, void* d_ws, size_t ws_size,
                              hipStream_t stream) {
    const float* z = (const float*)d_in[0];
    const int B = in_sizes[0] / 96;          // 6 * N_GAUSS = 96 floats per row
    float* out_mean = (float*)d_out;                              // B*16*9 floats
    float* out_logvar = (float*)d_out + (size_t)B * 16 * 9;       // B*16*3 floats

    const int nthreads = B * 4;              // one thread per 4 gaussians
    const int grid = nthreads / BLOCK;       // B*4 = 1,048,576 -> 4096 blocks (exact)
    so3_encode_kernel<<<grid, BLOCK, 0, stream>>>(z, out_mean, out_logvar);
}